// Round 1
// baseline (10737.489 us; speedup 1.0000x reference)
//
#include <hip/hip_runtime.h>

#define B_ 64
#define T_ 2048
#define I_ 256
#define H_ 512
#define O_ 256
#define GBC 2            // batch groups
#define GHC 32           // hidden-slice groups
#define MB (B_/GBC)      // 32 rows per WG
#define HS (H_/GHC)      // 16 hidden units per WG
#define NC (4*HS)        // 64 gate cols per WG
#define KK (I_+H_)       // 768 fused K (x | h)
#define KSTEPS (KK/32)   // 24 MFMA K-steps
#define AROWB ((KK+8)*2) // 1552 B per A row (pad 8 bf16 -> 2-way-free LDS banks)
#define GSTR 68          // gates LDS row stride (pad)

typedef __attribute__((ext_vector_type(8))) short short8;
typedef __attribute__((ext_vector_type(4))) float f32x4;
typedef __attribute__((ext_vector_type(4))) float float4v;

__device__ __forceinline__ unsigned short f2bf(float f) {
  union { float f; unsigned u; } v; v.f = f;
  unsigned r = v.u + 0x7fffu + ((v.u >> 16) & 1u);   // RNE
  return (unsigned short)(r >> 16);
}

// ---------------- init: zero hbuf[0..1] + stamps ----------------
__global__ void init_kernel(unsigned int* __restrict__ p, int n4) {
  int i = blockIdx.x * 256 + threadIdx.x;
  if (i < n4) p[i] = 0u;
}

// ---------------- weight/bias repack: Wcat[gh][c][k] bf16, col-major-per-WG ----------------
__global__ void prep_kernel(const float* __restrict__ Wx, const float* __restrict__ Wh,
                            const float* __restrict__ bias,
                            unsigned short* __restrict__ Wcat, float* __restrict__ bcat) {
  int idx = blockIdx.x * 256 + threadIdx.x;      // over [KK][2048], exact
  int k = idx >> 11;
  int gcol = idx & 2047;
  float v = (k < I_) ? Wx[k * 2048 + gcol] : Wh[(k - I_) * 2048 + gcol];
  int gate = gcol >> 9, j = gcol & 511;
  int gh = j >> 4, jj = j & 15;
  int c = (gate << 4) | jj;                      // local col = gate*16+jj
  Wcat[((size_t)(gh * NC + c) * KK) + k] = f2bf(v);
  if (k == 0) bcat[gh * NC + c] = bias[gcol];
}

// ---------------- persistent LSTM recurrence ----------------
__global__ __launch_bounds__(512, 2) void lstm_kernel(
    const float* __restrict__ x,
    const unsigned short* __restrict__ Wcat,
    const float* __restrict__ bcat,
    unsigned short* __restrict__ hbuf,   // [2][B_][H_] bf16
    int* __restrict__ stamps,            // [2][64]  idx = buf*64 + gb*32 + gh
    float* __restrict__ hout, float* __restrict__ cout)
{
  __shared__ __align__(16) char Alds[MB * AROWB];  // 49,664 B  A = [x_t | h] bf16
  __shared__ float gates[MB * GSTR];               //  8,704 B

  const int tid = threadIdx.x;
  const int wg = blockIdx.x;
  const int gb = wg >> 5, gh = wg & 31;
  const int bbase = gb * MB;
  const int hbase = gh * HS;
  const int lane = tid & 63, wid = tid >> 6;
  const int mt = wid >> 2, nt = wid & 3;           // 2 M-tiles x 4 N-tiles = 8 waves

  // --- W fragments: resident in VGPRs for the whole kernel (24 x 16B = 96 VGPR)
  short8 wfrag[KSTEPS];
  {
    const int col = nt * 16 + (lane & 15);
    const short8* wsrc = reinterpret_cast<const short8*>(
        Wcat + (size_t)(gh * NC + col) * KK + ((lane >> 4) * 8));
#pragma unroll
    for (int kk = 0; kk < KSTEPS; ++kk) wfrag[kk] = wsrc[kk * 4];
  }
  const float bias_l = bcat[gh * NC + nt * 16 + (lane & 15)];

  const int srow = tid >> 4, sseg = tid & 15;      // h-staging mapping
  const int crow = tid >> 4, cjj = tid & 15;       // combine mapping (1 cell/thread)
  float creg = 0.f;
  int spin_budget = 1 << 22;                       // fail-fast instead of hang

  for (int s = 1; s <= T_; ++s) {
    const int bprev = (s - 1) & 1, bcur = s & 1;

    // ---- phase A: wave0 spins on producer stamps; waves 4-7 stage x_t (independent of h)
    if (wid == 0) {
      int* sp = stamps + bprev * 64 + gb * 32 + (lane & 31);
      const int target = s - 1;
      while (__hip_atomic_load(sp, __ATOMIC_ACQUIRE, __HIP_MEMORY_SCOPE_AGENT) < target) {
        if (--spin_budget < 0) break;
      }
    } else if (tid >= 256) {
      const int slot = tid - 256;                  // 256 threads cover [32][256] fp32
      const int row = slot >> 3;
      const int k0 = (slot & 7) * 32;
      const float4v* xs = reinterpret_cast<const float4v*>(
          x + ((size_t)(bbase + row) * T_ + (s - 1)) * I_ + k0);
      const int ab = row * AROWB + k0 * 2;
#pragma unroll
      for (int c4 = 0; c4 < 4; ++c4) {
        float4v a = xs[2 * c4], b4 = xs[2 * c4 + 1];
        short8 o;
        o[0] = (short)f2bf(a[0]);  o[1] = (short)f2bf(a[1]);
        o[2] = (short)f2bf(a[2]);  o[3] = (short)f2bf(a[3]);
        o[4] = (short)f2bf(b4[0]); o[5] = (short)f2bf(b4[1]);
        o[6] = (short)f2bf(b4[2]); o[7] = (short)f2bf(b4[3]);
        *reinterpret_cast<short8*>(&Alds[ab + c4 * 16]) = o;
      }
    }
    __syncthreads();

    // ---- phase B: stage h_{s-1} (all 512 threads, 64B each, coalesced)
    {
      const short8* hs8 = reinterpret_cast<const short8*>(
          hbuf + (size_t)bprev * B_ * H_ + (size_t)(bbase + srow) * H_ + sseg * 32);
      short8 v0 = hs8[0], v1 = hs8[1], v2 = hs8[2], v3 = hs8[3];
      const int ab = srow * AROWB + (I_ + sseg * 32) * 2;
      *reinterpret_cast<short8*>(&Alds[ab +  0]) = v0;
      *reinterpret_cast<short8*>(&Alds[ab + 16]) = v1;
      *reinterpret_cast<short8*>(&Alds[ab + 32]) = v2;
      *reinterpret_cast<short8*>(&Alds[ab + 48]) = v3;
    }
    __syncthreads();

    // ---- phase C: GEMM  gates[mt-tile][nt-tile] += A x Wfrag  (bias pre-loaded into acc)
    {
      f32x4 acc = {bias_l, bias_l, bias_l, bias_l};
      const int abase = (mt * 16 + (lane & 15)) * AROWB + ((lane >> 4) * 8) * 2;
#pragma unroll
      for (int kk = 0; kk < KSTEPS; ++kk) {
        short8 a = *reinterpret_cast<const short8*>(&Alds[abase + kk * 64]);
        acc = __builtin_amdgcn_mfma_f32_16x16x32_bf16(a, wfrag[kk], acc, 0, 0, 0);
      }
      const int col = nt * 16 + (lane & 15);
      const int r0 = mt * 16 + ((lane >> 4) << 2);
      gates[(r0 + 0) * GSTR + col] = acc[0];
      gates[(r0 + 1) * GSTR + col] = acc[1];
      gates[(r0 + 2) * GSTR + col] = acc[2];
      gates[(r0 + 3) * GSTR + col] = acc[3];
    }
    __syncthreads();

    // ---- phase D: gate nonlinearities + cell update (1 (b,j) cell per thread)
    {
      const float* grow = &gates[crow * GSTR];
      float ig = grow[cjj], fg = grow[16 + cjj], gg = grow[32 + cjj], og = grow[48 + cjj];
      float i_ = 1.f / (1.f + __expf(-ig));
      float f_ = 1.f / (1.f + __expf(-fg));
      float g_ = 1.f - 2.f / (__expf(2.f * gg) + 1.f);   // tanh
      float o_ = 1.f / (1.f + __expf(-og));
      creg = f_ * creg + i_ * g_;
      float hv = o_ * (1.f - 2.f / (__expf(2.f * creg) + 1.f));
      hbuf[(size_t)bcur * B_ * H_ + (size_t)(bbase + crow) * H_ + hbase + cjj] = f2bf(hv);
      if (s == T_) {
        hout[(bbase + crow) * H_ + hbase + cjj] = hv;
        cout[(bbase + crow) * H_ + hbase + cjj] = creg;
      }
    }
    __syncthreads();   // drains vmcnt(0): all h-writes in L2 before release

    // ---- phase E: publish (release flushes XCD L2 -> device-visible)
    if (tid == 0)
      __hip_atomic_store(stamps + bcur * 64 + gb * 32 + gh, s,
                         __ATOMIC_RELEASE, __HIP_MEMORY_SCOPE_AGENT);
  }
}

// ---------------- final FC: y = h_T @ fc_w^T + fc_b ----------------
__global__ void fc_kernel(const float* __restrict__ hT, const float* __restrict__ fcw,
                          const float* __restrict__ fcb, float* __restrict__ y) {
  __shared__ float hr[H_];
  const int b = blockIdx.x, o = threadIdx.x;
  hr[o] = hT[b * H_ + o];
  hr[o + 256] = hT[b * H_ + 256 + o];
  __syncthreads();
  const float4v* w = reinterpret_cast<const float4v*>(fcw + (size_t)o * H_);
  const float4v* h4 = reinterpret_cast<const float4v*>(hr);
  float s0 = 0.f, s1 = 0.f, s2 = 0.f, s3 = 0.f;
#pragma unroll 8
  for (int k = 0; k < H_ / 4; ++k) {
    float4v wv = w[k], hv = h4[k];
    s0 += wv[0] * hv[0]; s1 += wv[1] * hv[1];
    s2 += wv[2] * hv[2]; s3 += wv[3] * hv[3];
  }
  y[b * O_ + o] = s0 + s1 + s2 + s3 + fcb[o];
}

extern "C" void kernel_launch(void* const* d_in, const int* in_sizes, int n_in,
                              void* d_out, int out_size, void* d_ws, size_t ws_size,
                              hipStream_t stream) {
  const float* x    = (const float*)d_in[0];
  const float* Wx   = (const float*)d_in[1];
  const float* Wh   = (const float*)d_in[2];
  const float* bias = (const float*)d_in[3];
  const float* fcw  = (const float*)d_in[4];
  const float* fcb  = (const float*)d_in[5];
  float* out = (float*)d_out;                 // [y 16384 | h 32768 | c 32768]

  char* ws = (char*)d_ws;
  unsigned short* Wcat = (unsigned short*)ws;                       // 3,145,728 B
  float* bcat          = (float*)(ws + 3145728);                    //     8,192 B
  unsigned short* hbuf = (unsigned short*)(ws + 3145728 + 8192);    //   131,072 B
  int* stamps          = (int*)(ws + 3145728 + 8192 + 131072);      //       512 B

  // zero hbuf + stamps (contiguous, 131,584 B = 32,896 dwords) — every call (stamps persist!)
  init_kernel<<<dim3(129), dim3(256), 0, stream>>>((unsigned int*)hbuf, 32896);
  // repack weights to bf16 [32][64][768] + bias [32][64] — every call (no static state allowed)
  prep_kernel<<<dim3((KK * 2048) / 256), dim3(256), 0, stream>>>(Wx, Wh, bias, Wcat, bcat);
  // persistent recurrence: 64 WGs (2 batch groups x 32 hidden slices), 512 threads
  lstm_kernel<<<dim3(GBC * GHC), dim3(512), 0, stream>>>(
      x, Wcat, bcat, hbuf, stamps, out + 16384, out + 16384 + 32768);
  // final projection
  fc_kernel<<<dim3(B_), dim3(256), 0, stream>>>(out + 16384, fcw, fcb, out);
}

// Round 2
// 8414.971 us; speedup vs baseline: 1.2760x; 1.2760x over previous
//
#include <hip/hip_runtime.h>

#define B_ 64
#define T_ 2048
#define I_ 256
#define H_ 512
#define O_ 256
#define GBC 2            // batch groups
#define GHC 32           // hidden-slice groups
#define MB (B_/GBC)      // 32 rows per WG
#define HS (H_/GHC)      // 16 hidden units per WG
#define NC (4*HS)        // 64 gate cols per WG
#define KK (I_+H_)       // 768 fused K (x | h)
#define KSTEPS (KK/32)   // 24 MFMA K-steps
#define AROWB ((KK+8)*2) // 1552 B per A row (row stride 388 dwords ≡ 4 mod 32)
#define GSTR 68          // gates LDS row stride (pad)
#define SPAD 32          // stamp padding: 32 ints = 128 B line per producer

typedef __attribute__((ext_vector_type(8))) short short8;
typedef __attribute__((ext_vector_type(4))) float f32x4;
typedef __attribute__((ext_vector_type(4))) float float4v;

__device__ __forceinline__ unsigned short f2bf(float f) {
  union { float f; unsigned u; } v; v.f = f;
  unsigned r = v.u + 0x7fffu + ((v.u >> 16) & 1u);   // RNE
  return (unsigned short)(r >> 16);
}

// ---------------- init: zero hbuf[0..1] + stamps ----------------
__global__ void init_kernel(unsigned int* __restrict__ p, int n4) {
  int i = blockIdx.x * 256 + threadIdx.x;
  if (i < n4) p[i] = 0u;
}

// ---------------- weight/bias repack: Wcat[gh][c][k] bf16 ----------------
__global__ void prep_kernel(const float* __restrict__ Wx, const float* __restrict__ Wh,
                            const float* __restrict__ bias,
                            unsigned short* __restrict__ Wcat, float* __restrict__ bcat) {
  int idx = blockIdx.x * 256 + threadIdx.x;      // over [KK][2048], exact
  int k = idx >> 11;
  int gcol = idx & 2047;
  float v = (k < I_) ? Wx[k * 2048 + gcol] : Wh[(k - I_) * 2048 + gcol];
  int gate = gcol >> 9, j = gcol & 511;
  int gh = j >> 4, jj = j & 15;
  int c = (gate << 4) | jj;                      // local col = gate*16+jj
  Wcat[((size_t)(gh * NC + c) * KK) + k] = f2bf(v);
  if (k == 0) bcat[gh * NC + c] = bias[gcol];
}

// ---------------- persistent LSTM recurrence ----------------
__global__ __launch_bounds__(512, 2) void lstm_kernel(
    const float* __restrict__ x,
    const unsigned short* __restrict__ Wcat,
    const float* __restrict__ bcat,
    unsigned short* hbuf,                // [2][B_][H_] bf16 (LLC-coherent traffic)
    int* stamps,                         // [2][64][SPAD]
    float* __restrict__ hout, float* __restrict__ cout)
{
  __shared__ __align__(16) char Alds[MB * AROWB];  // 49,664 B  A = [x_t | h] bf16
  __shared__ float gates[MB * GSTR];               //  8,704 B

  const int tid = threadIdx.x;
  const int wg = blockIdx.x;
  const int gb = wg >> 5, gh = wg & 31;
  const int bbase = gb * MB;
  const int hbase = gh * HS;
  const int lane = tid & 63, wid = tid >> 6;
  const int mt = wid >> 2, nt = wid & 3;           // 2 M-tiles x 4 N-tiles = 8 waves

  // --- W fragments: resident in VGPRs for the whole kernel (24 x 16B = 96 VGPR)
  short8 wfrag[KSTEPS];
  {
    const int col = nt * 16 + (lane & 15);
    const short8* wsrc = reinterpret_cast<const short8*>(
        Wcat + (size_t)(gh * NC + col) * KK + ((lane >> 4) * 8));
#pragma unroll
    for (int kk = 0; kk < KSTEPS; ++kk) wfrag[kk] = wsrc[kk * 4];
  }
  const float bias_l = bcat[gh * NC + nt * 16 + (lane & 15)];
  // forbid rematerialization of the wfrag loads inside the loop
  asm volatile("" ::: "memory");

  const int crow = tid >> 4, cjj = tid & 15;       // combine mapping (1 cell/thread)
  const int abase = (mt * 16 + (lane & 15)) * AROWB + ((lane >> 4) * 16);
  float creg = 0.f;
  int spin_budget = 1 << 24;                       // fail-fast instead of hang

  for (int s = 1; s <= T_; ++s) {
    const int bprev = (s - 1) & 1, bcur = s & 1;

    // ---- phase A: wave0 lanes 0-31 spin (relaxed, no cache maintenance);
    //               waves 3-6 stage x_t (bf16) into A x-region, conflict-free rows
    if (wid == 0) {
      if (lane < 32) {
        int* sp = stamps + ((size_t)bprev * 64 + gb * 32 + lane) * SPAD;
        const int target = s - 1;
        while (__hip_atomic_load(sp, __ATOMIC_RELAXED, __HIP_MEMORY_SCOPE_AGENT) < target) {
          if (--spin_budget < 0) break;
        }
      }
    } else if (wid >= 3 && wid <= 6) {
      const int wx = wid - 3;
#pragma unroll
      for (int i = 0; i < 8; ++i) {
        const int row = wx * 8 + i;
        const float4v xv = *reinterpret_cast<const float4v*>(
            x + ((size_t)(bbase + row) * T_ + (s - 1)) * I_ + 4 * lane);
        union { unsigned short u[4]; unsigned long long ll; } p;
        p.u[0] = f2bf(xv[0]); p.u[1] = f2bf(xv[1]);
        p.u[2] = f2bf(xv[2]); p.u[3] = f2bf(xv[3]);
        *reinterpret_cast<unsigned long long*>(&Alds[row * AROWB + 8 * lane]) = p.ll;
      }
    }
    __syncthreads();   // B1

    // ---- phase B/C-x: issue h loads (LLC-direct), overlap with x-part GEMM
    unsigned long long hv[8];
    {
      const int r0 = wid * 4;
#pragma unroll
      for (int i = 0; i < 8; ++i) {
        const int row = r0 + (i >> 1), hh = i & 1;
        unsigned long long* hp = reinterpret_cast<unsigned long long*>(
            hbuf + (size_t)bprev * B_ * H_ + (size_t)(bbase + row) * H_) + hh * 64 + lane;
        hv[i] = __hip_atomic_load(hp, __ATOMIC_RELAXED, __HIP_MEMORY_SCOPE_AGENT);
      }
    }
    f32x4 acc0 = {bias_l, bias_l, bias_l, bias_l};
#pragma unroll
    for (int kk = 0; kk < 8; ++kk) {             // x-part: K = 0..255
      short8 a = *reinterpret_cast<const short8*>(&Alds[abase + kk * 64]);
      acc0 = __builtin_amdgcn_mfma_f32_16x16x32_bf16(a, wfrag[kk], acc0, 0, 0, 0);
    }
    {
      const int r0 = wid * 4;
#pragma unroll
      for (int i = 0; i < 8; ++i) {              // stage h (compiler inserts vmcnt wait)
        const int row = r0 + (i >> 1), hh = i & 1;
        *reinterpret_cast<unsigned long long*>(
            &Alds[row * AROWB + 512 + hh * 512 + 8 * lane]) = hv[i];
      }
    }
    __syncthreads();   // B2

    // ---- phase C-h: h-part GEMM (K = 256..767), 2-accumulator split
    {
      f32x4 acc1 = {0.f, 0.f, 0.f, 0.f};
#pragma unroll
      for (int kk = 8; kk < KSTEPS; kk += 2) {
        short8 a0 = *reinterpret_cast<const short8*>(&Alds[abase + kk * 64]);
        acc0 = __builtin_amdgcn_mfma_f32_16x16x32_bf16(a0, wfrag[kk], acc0, 0, 0, 0);
        short8 a1 = *reinterpret_cast<const short8*>(&Alds[abase + (kk + 1) * 64]);
        acc1 = __builtin_amdgcn_mfma_f32_16x16x32_bf16(a1, wfrag[kk + 1], acc1, 0, 0, 0);
      }
      f32x4 acc = acc0 + acc1;
      const int col = nt * 16 + (lane & 15);
      const int r0 = mt * 16 + ((lane >> 4) << 2);
      gates[(r0 + 0) * GSTR + col] = acc[0];
      gates[(r0 + 1) * GSTR + col] = acc[1];
      gates[(r0 + 2) * GSTR + col] = acc[2];
      gates[(r0 + 3) * GSTR + col] = acc[3];
    }
    __syncthreads();   // B3

    // ---- phase D: gate nonlinearities + cell update; h published via
    //      relaxed agent atomics (write-through to LLC, no fences)
    {
      const float* grow = &gates[crow * GSTR];
      float ig = grow[cjj], fg = grow[16 + cjj], gg = grow[32 + cjj], og = grow[48 + cjj];
      float i_ = 1.f / (1.f + __expf(-ig));
      float f_ = 1.f / (1.f + __expf(-fg));
      float g_ = 1.f - 2.f / (__expf(2.f * gg) + 1.f);   // tanh
      float o_ = 1.f / (1.f + __expf(-og));
      creg = f_ * creg + i_ * g_;
      float hvf = o_ * (1.f - 2.f / (__expf(2.f * creg) + 1.f));
      unsigned mine = f2bf(hvf);
      unsigned other = __shfl_xor(mine, 1);
      if ((tid & 1) == 0) {
        unsigned packed = (mine & 0xffffu) | (other << 16);
        unsigned* hp = reinterpret_cast<unsigned*>(
            hbuf + (size_t)bcur * B_ * H_ + (size_t)(bbase + crow) * H_ + hbase + cjj);
        __hip_atomic_store(hp, packed, __ATOMIC_RELAXED, __HIP_MEMORY_SCOPE_AGENT);
      }
      if (s == T_) {
        hout[(bbase + crow) * H_ + hbase + cjj] = hvf;
        cout[(bbase + crow) * H_ + hbase + cjj] = creg;
      }
    }
    __syncthreads();   // B4: per-wave vmcnt(0) drain -> all h stores at LLC

    // ---- phase E: publish (relaxed; ordering established by B4's drain)
    if (tid == 0)
      __hip_atomic_store(stamps + ((size_t)bcur * 64 + gb * 32 + gh) * SPAD, s,
                         __ATOMIC_RELAXED, __HIP_MEMORY_SCOPE_AGENT);
  }
}

// ---------------- final FC: y = h_T @ fc_w^T + fc_b ----------------
__global__ void fc_kernel(const float* __restrict__ hT, const float* __restrict__ fcw,
                          const float* __restrict__ fcb, float* __restrict__ y) {
  __shared__ float hr[H_];
  const int b = blockIdx.x, o = threadIdx.x;
  hr[o] = hT[b * H_ + o];
  hr[o + 256] = hT[b * H_ + 256 + o];
  __syncthreads();
  const float4v* w = reinterpret_cast<const float4v*>(fcw + (size_t)o * H_);
  const float4v* h4 = reinterpret_cast<const float4v*>(hr);
  float s0 = 0.f, s1 = 0.f, s2 = 0.f, s3 = 0.f;
#pragma unroll 8
  for (int k = 0; k < H_ / 4; ++k) {
    float4v wv = w[k], hv = h4[k];
    s0 += wv[0] * hv[0]; s1 += wv[1] * hv[1];
    s2 += wv[2] * hv[2]; s3 += wv[3] * hv[3];
  }
  y[b * O_ + o] = s0 + s1 + s2 + s3 + fcb[o];
}

extern "C" void kernel_launch(void* const* d_in, const int* in_sizes, int n_in,
                              void* d_out, int out_size, void* d_ws, size_t ws_size,
                              hipStream_t stream) {
  const float* x    = (const float*)d_in[0];
  const float* Wx   = (const float*)d_in[1];
  const float* Wh   = (const float*)d_in[2];
  const float* bias = (const float*)d_in[3];
  const float* fcw  = (const float*)d_in[4];
  const float* fcb  = (const float*)d_in[5];
  float* out = (float*)d_out;                 // [y 16384 | h 32768 | c 32768]

  char* ws = (char*)d_ws;
  unsigned short* Wcat = (unsigned short*)ws;                       // 3,145,728 B
  float* bcat          = (float*)(ws + 3145728);                    //     8,192 B
  unsigned short* hbuf = (unsigned short*)(ws + 3145728 + 8192);    //   131,072 B
  int* stamps          = (int*)(ws + 3145728 + 8192 + 131072);      //    16,384 B

  // zero hbuf + stamps (147,456 B = 36,864 dwords) — every call (stamps persist!)
  init_kernel<<<dim3(144), dim3(256), 0, stream>>>((unsigned int*)hbuf, 36864);
  // repack weights to bf16 [32][64][768] + bias [32][64]
  prep_kernel<<<dim3((KK * 2048) / 256), dim3(256), 0, stream>>>(Wx, Wh, bias, Wcat, bcat);
  // persistent recurrence: 64 WGs (2 batch groups x 32 hidden slices), 512 threads
  lstm_kernel<<<dim3(GBC * GHC), dim3(512), 0, stream>>>(
      x, Wcat, bcat, hbuf, stamps, out + 16384, out + 16384 + 32768);
  // final projection
  fc_kernel<<<dim3(B_), dim3(256), 0, stream>>>(out + 16384, fcw, fcb, out);
}